// Round 5
// baseline (725.835 us; speedup 1.0000x reference)
//
#include <hip/hip_runtime.h>

typedef unsigned short u16;
typedef unsigned int   u32;
typedef short  s16x8 __attribute__((ext_vector_type(8)));
typedef float  f32x4 __attribute__((ext_vector_type(4)));

__device__ __forceinline__ u16 f2bf(float f) {
    union { float f; u32 i; } x; x.f = f;
    u32 r = x.i + 0x7FFFu + ((x.i >> 16) & 1u);   // RNE
    return (u16)(r >> 16);
}

// async global->LDS, 16B per lane; lds base wave-uniform (HW adds lane*16)
__device__ __forceinline__ void gld16(const void* g, void* l) {
    __builtin_amdgcn_global_load_lds((const __attribute__((address_space(1))) void*)g,
                                     (__attribute__((address_space(3))) void*)l,
                                     16, 0, 0);
}

// ---------------------------------------------------------------------------
// elementwise fp32 -> bf16 cast
// ---------------------------------------------------------------------------
__global__ __launch_bounds__(256)
void cast_bf16(const float* __restrict__ in, u16* __restrict__ out, int n4) {
    int g = blockIdx.x * 256 + threadIdx.x;
    if (g >= n4) return;
    float4 v = ((const float4*)in)[g];
    ushort4 o; o.x = f2bf(v.x); o.y = f2bf(v.y); o.z = f2bf(v.z); o.w = f2bf(v.w);
    ((ushort4*)out)[g] = o;
}

// ---------------------------------------------------------------------------
// B[K][N] fp32 -> Bt[N][K] bf16, 32x32 LDS tile. grid(N/32, K/32)
// ---------------------------------------------------------------------------
__global__ __launch_bounds__(256)
void tconv(const float* __restrict__ B, u16* __restrict__ Bt, int K, int N) {
    __shared__ float T[32][33];
    int n0 = blockIdx.x * 32, k0 = blockIdx.y * 32;
    int t = threadIdx.x;
    int r = t >> 3, c4 = (t & 7) * 4;
    float4 v = *(const float4*)&B[(size_t)(k0 + r) * N + n0 + c4];
    T[r][c4 + 0] = v.x; T[r][c4 + 1] = v.y; T[r][c4 + 2] = v.z; T[r][c4 + 3] = v.w;
    __syncthreads();
    ushort4 o;
    o.x = f2bf(T[c4 + 0][r]); o.y = f2bf(T[c4 + 1][r]);
    o.z = f2bf(T[c4 + 2][r]); o.w = f2bf(T[c4 + 3][r]);
    *(ushort4*)&Bt[(size_t)(n0 + r) * K + k0 + c4] = o;
}

// ---------------------------------------------------------------------------
// cache_k fp32 [t][8][128] -> Kc bf16 [kh][4096_t][128] (tokens 0..2047)
// ---------------------------------------------------------------------------
__global__ __launch_bounds__(256)
void kcache_conv(const float* __restrict__ ck, u16* __restrict__ Kc) {
    int g = blockIdx.x * 256 + threadIdx.x;
    int d = (g & 31) * 4, kh = (g >> 5) & 7, t = g >> 8;
    float4 v = *(const float4*)&ck[(size_t)t * 1024 + kh * 128 + d];
    ushort4 o; o.x = f2bf(v.x); o.y = f2bf(v.y); o.z = f2bf(v.z); o.w = f2bf(v.w);
    *(ushort4*)&Kc[(size_t)kh * 524288 + (size_t)t * 128 + d] = o;
}

// ---------------------------------------------------------------------------
// cache_v fp32 [t][8][128] -> Vt bf16 [kh][128_hd][4096_t] (tokens 0..2047)
// ---------------------------------------------------------------------------
__global__ __launch_bounds__(256)
void vcache_conv(const float* __restrict__ cv, u16* __restrict__ Vt) {
    __shared__ float T[32][33];
    int t0 = blockIdx.x * 32, d0 = blockIdx.y * 32, kh = blockIdx.z;
    int t = threadIdx.x;
    int r = t >> 3, c4 = (t & 7) * 4;
    float4 v = *(const float4*)&cv[(size_t)(t0 + r) * 1024 + kh * 128 + d0 + c4];
    T[r][c4 + 0] = v.x; T[r][c4 + 1] = v.y; T[r][c4 + 2] = v.z; T[r][c4 + 3] = v.w;
    __syncthreads();
    ushort4 o;
    o.x = f2bf(T[c4 + 0][r]); o.y = f2bf(T[c4 + 1][r]);
    o.z = f2bf(T[c4 + 2][r]); o.w = f2bf(T[c4 + 3][r]);
    *(ushort4*)&Vt[(size_t)(kh * 128 + d0 + r) * 4096 + t0 + c4] = o;
}

// ---------------------------------------------------------------------------
// Shared MFMA GEMM main loop: acc[4][4] += A[m0..+128][K] @ Bt[0..128][K]^T.
// ---------------------------------------------------------------------------
__device__ __forceinline__ void gemm_core(const u16* __restrict__ A,
                                          const u16* __restrict__ Bt,
                                          int K, int m0,
                                          u16* As, u16* Bs, f32x4 acc[4][4])
{
    const int tid = threadIdx.x;
    const int lane = tid & 63, w = tid >> 6;
    const int quad = lane >> 4, l15 = lane & 15;
    const int mw = (w >> 1) * 64, nw = (w & 1) * 64;
    const int lrow = tid >> 2;
    const int lcol = ((tid & 3) ^ (lrow & 3)) * 8;
    const int rsw = l15 & 3;

    for (int k0 = 0; k0 < K; k0 += 32) {
        __syncthreads();
        gld16(A  + (size_t)(m0 +      lrow) * K + k0 + lcol, &As[w * 512]);
        gld16(A  + (size_t)(m0 + 64 + lrow) * K + k0 + lcol, &As[2048 + w * 512]);
        gld16(Bt + (size_t)(           lrow) * K + k0 + lcol, &Bs[w * 512]);
        gld16(Bt + (size_t)(      64 + lrow) * K + k0 + lcol, &Bs[2048 + w * 512]);
        __syncthreads();
        s16x8 af[4], bf[4];
        #pragma unroll
        for (int i = 0; i < 4; ++i)
            af[i] = *(const s16x8*)&As[(mw + i * 16 + l15) * 32 + (quad ^ rsw) * 8];
        #pragma unroll
        for (int j = 0; j < 4; ++j)
            bf[j] = *(const s16x8*)&Bs[(nw + j * 16 + l15) * 32 + (quad ^ rsw) * 8];
        #pragma unroll
        for (int i = 0; i < 4; ++i)
            #pragma unroll
            for (int j = 0; j < 4; ++j)
                acc[i][j] = __builtin_amdgcn_mfma_f32_16x16x32_bf16(
                    af[i], bf[j], acc[i][j], 0, 0, 0);
    }
}

// ---------------------------------------------------------------------------
// Fused QKV GEMM: N = 4096(Q) + 1024(K) + 1024(V) = 6144, grid(48,16).
// ---------------------------------------------------------------------------
__global__ __launch_bounds__(256, 2)
void gemm_qkv(const u16* __restrict__ A, const u16* __restrict__ Wq,
              const u16* __restrict__ Wk, const u16* __restrict__ Wv,
              u16* __restrict__ Qw, u16* __restrict__ Kc, u16* __restrict__ Vt,
              const float* __restrict__ rope)
{
    __shared__ u16 As[128 * 32];
    __shared__ u16 Bs[128 * 32];
    const int m0 = blockIdx.y * 128, n0 = blockIdx.x * 128;

    const u16* Bt;
    if (n0 < 4096)       Bt = Wq + (size_t)n0 * 4096;
    else if (n0 < 5120)  Bt = Wk + (size_t)(n0 - 4096) * 4096;
    else                 Bt = Wv + (size_t)(n0 - 5120) * 4096;

    f32x4 acc[4][4];
    #pragma unroll
    for (int i = 0; i < 4; ++i)
        #pragma unroll
        for (int j = 0; j < 4; ++j) acc[i][j] = (f32x4)0.f;

    gemm_core(A, Bt, 4096, m0, As, Bs, acc);

    const int lane = threadIdx.x & 63, w = threadIdx.x >> 6;
    const int quad = lane >> 4, l15 = lane & 15;
    const int mw = (w >> 1) * 64, nw = (w & 1) * 64;

    #pragma unroll
    for (int i = 0; i < 4; ++i) {
        #pragma unroll
        for (int j = 0; j < 4; ++j) {
            int mm = m0 + mw + i * 16 + quad * 4;
            int nn = n0 + nw + j * 16 + l15;
            if (nn < 4096) {
                #pragma unroll
                for (int r = 0; r < 4; ++r)
                    Qw[(size_t)(mm + r) * 4096 + nn] =
                        f2bf(acc[i][j][r] * rope[(size_t)(mm + r) * 128 + (nn & 127)]
                             * 0.08838834764831845f);
            } else if (nn < 5120) {
                #pragma unroll
                for (int r = 0; r < 4; ++r)
                    Kc[(size_t)((nn - 4096) >> 7) * 524288
                       + (size_t)(2048 + mm + r) * 128 + (nn & 127)] =
                        f2bf(acc[i][j][r] * rope[(size_t)(mm + r) * 128 + (nn & 127)]);
            } else {
                ushort4 o;
                o.x = f2bf(acc[i][j][0]); o.y = f2bf(acc[i][j][1]);
                o.z = f2bf(acc[i][j][2]); o.w = f2bf(acc[i][j][3]);
                *(ushort4*)&Vt[(size_t)(nn - 5120) * 4096 + 2048 + mm] = o;
            }
        }
    }
}

// ---------------------------------------------------------------------------
// Output GEMM: out = AO @ wo^T, fp32 out. grid(32,16).
// ---------------------------------------------------------------------------
__global__ __launch_bounds__(256, 2)
void gemm_wo(const u16* __restrict__ A, const u16* __restrict__ Bt,
             float* __restrict__ C)
{
    __shared__ u16 As[128 * 32];
    __shared__ u16 Bs[128 * 32];
    const int m0 = blockIdx.y * 128, n0 = blockIdx.x * 128;

    f32x4 acc[4][4];
    #pragma unroll
    for (int i = 0; i < 4; ++i)
        #pragma unroll
        for (int j = 0; j < 4; ++j) acc[i][j] = (f32x4)0.f;

    gemm_core(A, Bt + (size_t)n0 * 4096, 4096, m0, As, Bs, acc);

    const int lane = threadIdx.x & 63, w = threadIdx.x >> 6;
    const int quad = lane >> 4, l15 = lane & 15;
    const int mw = (w >> 1) * 64, nw = (w & 1) * 64;

    #pragma unroll
    for (int i = 0; i < 4; ++i)
        #pragma unroll
        for (int j = 0; j < 4; ++j) {
            int mm = m0 + mw + i * 16 + quad * 4;
            int nn = n0 + nw + j * 16 + l15;
            #pragma unroll
            for (int r = 0; r < 4; ++r)
                C[(size_t)(mm + r) * 4096 + nn] = acc[i][j][r];
        }
}

// ---------------------------------------------------------------------------
// MFMA flash attention, R10 = R9 structure with proven-safe components.
//   K/V fragments loaded DIRECTLY global->VGPR (wave-private, L2-local via
//   XCD pin) -- LDS holds only Pb (cross-wave), stride-40 (R2-proven 2-way
//   free), double-buffered: LDS 10240 B. LDS traffic/block-tile 60->20 KB.
//   R4 failure audit -> de-risked here: (1) softmax is the exact R3-proven
//   path (__expf + cvt_pk asm; inline-asm v_exp_f32 removed -- TRANS-op
//   wait-state hazard is invisible to the compiler inside asm blocks);
//   (2) full __syncthreads() per tile (vmcnt drain ~free here: only the
//   K-prefetch from last iter is in flight, needed immediately anyway);
//   (3) launch_bounds(256,3): reg budget ~140 VGPR, no spills, 3 blk/CU.
//   Pipeline per 32-key tile t:  sync | load V(t-32)->reg | prefetch
//   K(t+32)->alt reg set | S(t) | softmax -> Pb write | PV(t-32).
//   K reg sets alternate via unroll-2 with named registers (rule #20).
//   Tile count is always even. OOB prefetches (first V, last K) land in
//   adjacent ws regions (allocated, unused). Ls overlays PbBuf[0].
// ---------------------------------------------------------------------------
__global__ __launch_bounds__(256, 3)
void attn_mfma(const u16* __restrict__ Qw, const u16* __restrict__ Kc,
               const u16* __restrict__ Vt, u16* __restrict__ AO)
{
    __shared__ u16 PbBuf[2][64 * 40];   // [buf][q][key], stride 40 u16 = 80B

    const int tid = threadIdx.x;
    const int lane = tid & 63, w = tid >> 6;
    const int quad = lane >> 4, l15 = lane & 15;

    // XCD-aware remap: all 128 blocks of one kh land on one XCD (bid%8 = kh)
    const int bid = blockIdx.x + 32 * blockIdx.y;      // 0..1023
    const int kh = bid & 7;
    const int inner = bid >> 3;                        // 0..127
    const int h = kh * 4 + (inner & 3);
    const int q0 = (inner >> 2) * 64;

    const int kw = w & 1, qw = w >> 1;
    const size_t kvb = (size_t)kh * 524288;

    // Q fragments -> registers, once.
    s16x8 qreg[2][4];
    #pragma unroll
    for (int n = 0; n < 2; ++n)
        #pragma unroll
        for (int ks = 0; ks < 4; ++ks)
            qreg[n][ks] = *(const s16x8*)&Qw[(size_t)(q0 + qw * 32 + n * 16 + l15) * 4096
                                             + h * 128 + ks * 32 + quad * 8];

    f32x4 o[2][4];
    #pragma unroll
    for (int m = 0; m < 2; ++m)
        #pragma unroll
        for (int n = 0; n < 4; ++n) o[m][n] = (f32x4)0.f;
    float lacc[2] = {0.f, 0.f};

    // per-lane fragment base pointers (K: + t*128 + ks*32 ; V: + t)
    const u16* kfp  = Kc + kvb + (size_t)(kw * 16 + l15) * 128 + quad * 8;
    const u16* vfp0 = Vt + kvb + (size_t)(w * 32 + l15) * 4096 + quad * 8;
    const u16* vfp1 = vfp0 + (size_t)16 * 4096;

    const int kend = 2112 + q0;     // last needed key = 2048+q0+63

    u16* pb_wr = &PbBuf[0][0];
    u16* pb_rd = &PbBuf[1][0];

    // K fragment register sets (named; alternated by unroll-2 loop)
    s16x8 kA0, kA1, kA2, kA3, kB0, kB1, kB2, kB3;
    kA0 = *(const s16x8*)&kfp[0];
    kA1 = *(const s16x8*)&kfp[32];
    kA2 = *(const s16x8*)&kfp[64];
    kA3 = *(const s16x8*)&kfp[96];

#define AITER(T0, C0, C1, C2, C3, N0, N1, N2, N3)                              \
    {                                                                          \
        const int tt = (T0);                                                   \
        /* Pb(tt-32) visible; prior Pb reads done; K(tt) prefetch drained */   \
        __syncthreads();                                                       \
        /* V(tt-32) fragments, used by PV below (hidden under S+softmax) */    \
        s16x8 vf0 = *(const s16x8*)&vfp0[tt - 32];                             \
        s16x8 vf1 = *(const s16x8*)&vfp1[tt - 32];                             \
        /* prefetch K(tt+32) into the alternate register set */                \
        { const u16* knp = kfp + (size_t)(tt + 32) * 128;                      \
          N0 = *(const s16x8*)&knp[0];                                         \
          N1 = *(const s16x8*)&knp[32];                                        \
          N2 = *(const s16x8*)&knp[64];                                        \
          N3 = *(const s16x8*)&knp[96]; }                                      \
        /* S(tt): wave (kw,qw) -> keys [16kw,+16) x q [32qw,+32) */            \
        f32x4 sc0 = (f32x4)0.f, sc1 = (f32x4)0.f;                              \
        sc0 = __builtin_amdgcn_mfma_f32_16x16x32_bf16(C0, qreg[0][0], sc0, 0, 0, 0); \
        sc1 = __builtin_amdgcn_mfma_f32_16x16x32_bf16(C0, qreg[1][0], sc1, 0, 0, 0); \
        sc0 = __builtin_amdgcn_mfma_f32_16x16x32_bf16(C1, qreg[0][1], sc0, 0, 0, 0); \
        sc1 = __builtin_amdgcn_mfma_f32_16x16x32_bf16(C1, qreg[1][1], sc1, 0, 0, 0); \
        sc0 = __builtin_amdgcn_mfma_f32_16x16x32_bf16(C2, qreg[0][2], sc0, 0, 0, 0); \
        sc1 = __builtin_amdgcn_mfma_f32_16x16x32_bf16(C2, qreg[1][2], sc1, 0, 0, 0); \
        sc0 = __builtin_amdgcn_mfma_f32_16x16x32_bf16(C3, qreg[0][3], sc0, 0, 0, 0); \
        sc1 = __builtin_amdgcn_mfma_f32_16x16x32_bf16(C3, qreg[1][3], sc1, 0, 0, 0); \
        const bool maskt = (tt + 31 > 2048 + q0);                              \
        _Pragma("unroll")                                                      \
        for (int n2 = 0; n2 < 2; ++n2) {                                       \
            f32x4 s = n2 ? sc1 : sc0;                                          \
            float e0 = __expf(s[0]);                                           \
            float e1 = __expf(s[1]);                                           \
            float e2 = __expf(s[2]);                                           \
            float e3 = __expf(s[3]);                                           \
            if (maskt) {                                                       \
                int key = tt + kw * 16 + quad * 4;                             \
                int qv  = q0 + qw * 32 + n2 * 16 + l15;                        \
                if (key + 0 >= 2048 && key + 0 - 2048 > qv) e0 = 0.f;          \
                if (key + 1 >= 2048 && key + 1 - 2048 > qv) e1 = 0.f;          \
                if (key + 2 >= 2048 && key + 2 - 2048 > qv) e2 = 0.f;          \
                if (key + 3 >= 2048 && key + 3 - 2048 > qv) e3 = 0.f;          \
            }                                                                  \
            lacc[n2] += (e0 + e1) + (e2 + e3);                                 \
            u32 p0, p1;                                                        \
            asm("v_cvt_pk_bf16_f32 %0, %1, %2" : "=v"(p0) : "v"(e0), "v"(e1)); \
            asm("v_cvt_pk_bf16_f32 %0, %1, %2" : "=v"(p1) : "v"(e2), "v"(e3)); \
            uint2 pk; pk.x = p0; pk.y = p1;                                    \
            *(uint2*)&pb_wr[(qw * 32 + n2 * 16 + l15) * 40 + kw * 16 + quad * 4] = pk; \
        }                                                                      \
        /* PV(tt-32): V/P of previous tile; independent of S(tt) */            \
        if (tt) {                                                              \
            _Pragma("unroll")                                                  \
            for (int n = 0; n < 4; ++n) {                                      \
                s16x8 pf = *(const s16x8*)&pb_rd[(n * 16 + l15) * 40 + quad * 8]; \
                o[0][n] = __builtin_amdgcn_mfma_f32_16x16x32_bf16(vf0, pf, o[0][n], 0, 0, 0); \
                o[1][n] = __builtin_amdgcn_mfma_f32_16x16x32_bf16(vf1, pf, o[1][n], 0, 0, 0); \
            }                                                                  \
        }                                                                      \
        { u16* tp = pb_rd; pb_rd = pb_wr; pb_wr = tp; }                        \
    }

    for (int t0 = 0; t0 < kend; t0 += 64) {
        AITER(t0,      kA0, kA1, kA2, kA3, kB0, kB1, kB2, kB3)
        AITER(t0 + 32, kB0, kB1, kB2, kB3, kA0, kA1, kA2, kA3)
    }
#undef AITER

    // epilogue: PV of the final tile (Pb in pb_rd; tile count is even)
    __syncthreads();
    {
        s16x8 vf0 = *(const s16x8*)&vfp0[kend - 32];
        s16x8 vf1 = *(const s16x8*)&vfp1[kend - 32];
        #pragma unroll
        for (int n = 0; n < 4; ++n) {
            s16x8 pf = *(const s16x8*)&pb_rd[(n * 16 + l15) * 40 + quad * 8];
            o[0][n] = __builtin_amdgcn_mfma_f32_16x16x32_bf16(vf0, pf, o[0][n], 0, 0, 0);
            o[1][n] = __builtin_amdgcn_mfma_f32_16x16x32_bf16(vf1, pf, o[1][n], 0, 0, 0);
        }
    }

    // L totals: reduce over quads, publish per (kw, q), sum the two halves.
    // Ls overlays PbBuf[0] (dead: final Pb lives in PbBuf[1]).
    float* Ls = (float*)&PbBuf[0][0];           // [2][64]
    lacc[0] += __shfl_xor(lacc[0], 16); lacc[0] += __shfl_xor(lacc[0], 32);
    lacc[1] += __shfl_xor(lacc[1], 16); lacc[1] += __shfl_xor(lacc[1], 32);
    __syncthreads();
    if (lane < 16) {
        Ls[kw * 64 + qw * 32 +      lane] = lacc[0];
        Ls[kw * 64 + qw * 32 + 16 + lane] = lacc[1];
    }
    __syncthreads();

    #pragma unroll
    for (int n = 0; n < 4; ++n) {
        int qq = n * 16 + l15;
        float inv = 1.f / (Ls[qq] + Ls[64 + qq]);
        #pragma unroll
        for (int m = 0; m < 2; ++m) {
            ushort4 ov;
            ov.x = f2bf(o[m][n][0] * inv);
            ov.y = f2bf(o[m][n][1] * inv);
            ov.z = f2bf(o[m][n][2] * inv);
            ov.w = f2bf(o[m][n][3] * inv);
            *(ushort4*)&AO[(size_t)(q0 + qq) * 4096 + h * 128
                           + w * 32 + m * 16 + quad * 4] = ov;
        }
    }
}

// ---------------------------------------------------------------------------
// inputs (fp32): x, rope, mask, cache_k, cache_v, wq, wk, wv, wo
// ws (u16 units): xb 8.4M | W0 16.8M (wq^T -> wo^T) | W1 4.2M (wk^T) |
//                 Qw 8.4M | Kc 4.2M | Vt 4.2M | AO 8.4M (wv^T parks here)
// ---------------------------------------------------------------------------
extern "C" void kernel_launch(void* const* d_in, const int* in_sizes, int n_in,
                              void* d_out, int out_size, void* d_ws, size_t ws_size,
                              hipStream_t stream)
{
    const float* x      = (const float*)d_in[0];
    const float* rope   = (const float*)d_in[1];
    const float* cacheK = (const float*)d_in[3];
    const float* cacheV = (const float*)d_in[4];
    const float* wq     = (const float*)d_in[5];
    const float* wk     = (const float*)d_in[6];
    const float* wv     = (const float*)d_in[7];
    const float* wo     = (const float*)d_in[8];
    float* out = (float*)d_out;

    u16* xb = (u16*)d_ws;                    // [2048][4096]
    u16* W0 = xb + (size_t)8388608;          // [4096][4096] wq^T, later wo^T
    u16* W1 = W0 + (size_t)16777216;         // [1024][4096] wk^T
    u16* Qw = W1 + (size_t)4194304;          // [2048][4096] (rope*scale)
    u16* Kc = Qw + (size_t)8388608;          // [8][4096][128]
    u16* Vt = Kc + (size_t)4194304;          // [8][128][4096]
    u16* AO = Vt + (size_t)4194304;          // [2048][4096]; wv^T parks here first
    u16* Wv = AO;                            // [1024][4096] until attn runs

    dim3 blk(256);
    cast_bf16<<<dim3(8192), blk, 0, stream>>>(x, xb, 2097152);
    tconv<<<dim3(128, 128), blk, 0, stream>>>(wq, W0, 4096, 4096);
    tconv<<<dim3(32, 128), blk, 0, stream>>>(wk, W1, 4096, 1024);
    tconv<<<dim3(32, 128), blk, 0, stream>>>(wv, Wv, 4096, 1024);
    gemm_qkv<<<dim3(48, 16), blk, 0, stream>>>(xb, W0, W1, Wv, Qw, Kc, Vt, rope);
    kcache_conv<<<dim3(2048), blk, 0, stream>>>(cacheK, Kc);
    vcache_conv<<<dim3(64, 4, 8), blk, 0, stream>>>(cacheV, Vt);
    attn_mfma<<<dim3(32, 32), blk, 0, stream>>>(Qw, Kc, Vt, AO);
    tconv<<<dim3(128, 128), blk, 0, stream>>>(wo, W0, 4096, 4096);
    gemm_wo<<<dim3(32, 16), blk, 0, stream>>>(AO, W0, out);
}